// Round 18
// baseline (85.047 us; speedup 1.0000x reference)
//
#include <hip/hip_runtime.h>

typedef float  f32x4  __attribute__((ext_vector_type(4)));
typedef short  short8 __attribute__((ext_vector_type(8)));
typedef __bf16 bf16x8 __attribute__((ext_vector_type(8)));

#define DEV static __device__ __forceinline__
// sched_group_barrier masks: VALU=0x2, MFMA=0x8, VMEM_READ=0x20, VMEM_WRITE=0x40
#define SGB(m, n) __builtin_amdgcn_sched_group_barrier((m), (n), 0)

DEV f32x4 mfma16(short8 a, short8 b, f32x4 c) {
  return __builtin_amdgcn_mfma_f32_16x16x32_bf16(
      __builtin_bit_cast(bf16x8, a), __builtin_bit_cast(bf16x8, b), c, 0, 0, 0);
}

// split f32 into bf16 hi (truncated) + bf16 lo (RNE of residual)
DEV void splitf(float f, unsigned short& hi, unsigned short& lo) {
  unsigned u = __builtin_bit_cast(unsigned, f);
  hi = (unsigned short)(u >> 16);
  float hf = __builtin_bit_cast(float, u & 0xFFFF0000u);
  float r = f - hf;
  unsigned v = __builtin_bit_cast(unsigned, r);
  lo = (unsigned short)((v + 0x7FFFu + ((v >> 16) & 1u)) >> 16);
}

// RNE f32 -> bf16
DEV unsigned short rne16(float f) {
  unsigned v = __builtin_bit_cast(unsigned, f);
  return (unsigned short)((v + 0x7FFFu + ((v >> 16) & 1u)) >> 16);
}

#define DDIM 640
#define KCH  20                    // 640 / 32 k-chunks for GEMM1
#define MKP_ELEMS (KCH*2*4*64*8)   // 81920 ushorts = 160KB  (hi+lo planes)
#define MVP_OFF   MKP_ELEMS        // MvP: hi-only, 80KB

// Pack Mk (hi/lo fragment planes) and Mv^T (RNE hi-only) in MFMA fragment order.
// MkP: [c(20)][plane(2)][g(4)][lane(64)][j(8)] holds Mk[m=16g+(l&15)][d=32c+8*(l>>4)+j]
// MvP: [n(40)][c(2)][lane(64)][j(8)]           holds Mv[m=32c+8*(l>>4)+j][d=16n+(l&15)]
__global__ void ea_pack(const float* __restrict__ Mk, const float* __restrict__ Mv,
                        unsigned short* __restrict__ ws) {
  int tid = blockIdx.x * 256 + threadIdx.x;
  unsigned short* MkP = ws;
  unsigned short* MvP = ws + MVP_OFF;
  if (tid < 5120) {
    int c = tid >> 8;
    int g = (tid >> 6) & 3;
    int l = tid & 63;
    int t = l & 15, q = l >> 4;
    const float* src = Mk + (16*g + t) * DDIM + 32*c + 8*q;
    unsigned short* dh = MkP + (((c*2 + 0)*4 + g)*64 + l)*8;
    unsigned short* dl = MkP + (((c*2 + 1)*4 + g)*64 + l)*8;
#pragma unroll
    for (int j = 0; j < 8; ++j) splitf(src[j], dh[j], dl[j]);
  } else if (tid < 10240) {
    int s = tid - 5120;
    int n = s >> 7;
    int c = (s >> 6) & 1;
    int l = s & 63;
    int t = l & 15, q = l >> 4;
    const float* src = Mv + (32*c + 8*q) * DDIM + 16*n + t;
    unsigned short* dh = MvP + ((n*2 + c)*64 + l)*8;
#pragma unroll
    for (int j = 0; j < 8; ++j) dh[j] = rne16(src[j*DDIM]);
  }
}

// ---- GEMM1 helpers (R16/R17 structure, unchanged) ----
#define LOADX(X0, X1, c) { X0 = *(const f32x4*)(xp + 32*(c)); \
                           X1 = *(const f32x4*)(xp + 32*(c) + 4); }

#define LOADFA(c) { const unsigned short* p_ = MkP + (c)*4096 + l*8;         \
  fa0 = *(const short8*)(p_);        fa1 = *(const short8*)(p_ + 512);       \
  fa2 = *(const short8*)(p_ + 1024); fa3 = *(const short8*)(p_ + 1536);      \
  fa4 = *(const short8*)(p_ + 2048); fa5 = *(const short8*)(p_ + 2560);      \
  fa6 = *(const short8*)(p_ + 3072); fa7 = *(const short8*)(p_ + 3584); }

#define LOADFB(c) { const unsigned short* p_ = MkP + (c)*4096 + l*8;         \
  fb0 = *(const short8*)(p_);        fb1 = *(const short8*)(p_ + 512);       \
  fb2 = *(const short8*)(p_ + 1024); fb3 = *(const short8*)(p_ + 1536);      \
  fb4 = *(const short8*)(p_ + 2048); fb5 = *(const short8*)(p_ + 2560);      \
  fb6 = *(const short8*)(p_ + 3072); fb7 = *(const short8*)(p_ + 3584); }

#define SPLITX(X0, X1)                                                       \
  splitf(X0[0], ah.u[0], al.u[0]); splitf(X0[1], ah.u[1], al.u[1]);          \
  splitf(X0[2], ah.u[2], al.u[2]); splitf(X0[3], ah.u[3], al.u[3]);          \
  splitf(X1[0], ah.u[4], al.u[4]); splitf(X1[1], ah.u[5], al.u[5]);          \
  splitf(X1[2], ah.u[6], al.u[6]); splitf(X1[3], ah.u[7], al.u[7]);

#define MFMAS_A()                                                            \
  acc[0] = mfma16(ah.s, fa0, acc[0]); acc[1] = mfma16(ah.s, fa1, acc[1]);    \
  acc[2] = mfma16(ah.s, fa2, acc[2]); acc[3] = mfma16(ah.s, fa3, acc[3]);    \
  acc[0] = mfma16(al.s, fa0, acc[0]); acc[1] = mfma16(al.s, fa1, acc[1]);    \
  acc[2] = mfma16(al.s, fa2, acc[2]); acc[3] = mfma16(al.s, fa3, acc[3]);    \
  acc[0] = mfma16(ah.s, fa4, acc[0]); acc[1] = mfma16(ah.s, fa5, acc[1]);    \
  acc[2] = mfma16(ah.s, fa6, acc[2]); acc[3] = mfma16(ah.s, fa7, acc[3]);

#define MFMAS_B()                                                            \
  acc[0] = mfma16(ah.s, fb0, acc[0]); acc[1] = mfma16(ah.s, fb1, acc[1]);    \
  acc[2] = mfma16(ah.s, fb2, acc[2]); acc[3] = mfma16(ah.s, fb3, acc[3]);    \
  acc[0] = mfma16(al.s, fb0, acc[0]); acc[1] = mfma16(al.s, fb1, acc[1]);    \
  acc[2] = mfma16(al.s, fb2, acc[2]); acc[3] = mfma16(al.s, fb3, acc[3]);    \
  acc[0] = mfma16(ah.s, fb4, acc[0]); acc[1] = mfma16(ah.s, fb5, acc[1]);    \
  acc[2] = mfma16(ah.s, fb6, acc[2]); acc[3] = mfma16(ah.s, fb7, acc[3]);

// One wave per block (64 threads), 16 rows/wave, grid 4096 -> 16 blocks/CU.
// Independent waves, no barriers. GEMM1 frag ping-pong with SGB-pinned issue
// order; softmax in-register; W via XOR-swizzled LDS; GEMM2 SWAPPED operands
// (Mv-hi as A, W as B -> lane holds 4 consecutive d of one row) with paired
// f32x4 NT stores (128B-combinable row segments).
__global__
__attribute__((amdgpu_flat_work_group_size(64, 64), amdgpu_waves_per_eu(4, 4)))
void ea_main(const float* __restrict__ x,
             const unsigned short* __restrict__ MkP,
             const unsigned short* __restrict__ MvP,
             float* __restrict__ out) {
  __shared__ __align__(16) unsigned short Wh[16][64];
  __shared__ __align__(16) unsigned short Wl[16][64];
  const int l = threadIdx.x;          // 0..63
  const int t = l & 15;
  const int q = l >> 4;
  const long row0 = (long)blockIdx.x * 16;

  // ---------------- GEMM1: scores ----------------
  const float* xp = x + (row0 + t) * DDIM + 8*q;
  f32x4 acc[4];
#pragma unroll
  for (int g = 0; g < 4; ++g) acc[g] = (f32x4){0.f, 0.f, 0.f, 0.f};

  f32x4 x00,x01,x10,x11,x20,x21,x30,x31;
  short8 fa0,fa1,fa2,fa3,fa4,fa5,fa6,fa7;        // frag set A (even chunks)
  short8 fb0,fb1,fb2,fb3,fb4,fb5,fb6,fb7;        // frag set B (odd chunks)
  union { short8 s; unsigned short u[8]; } ah, al;

  LOADX(x00,x01, 0) LOADX(x10,x11, 1) LOADX(x20,x21, 2) LOADX(x30,x31, 3)
  LOADFA(0)

  // main iters cc = 0,4,8,12 (all have cc+4 <= 16 < 20: x prefetch active)
#pragma unroll
  for (int cc = 0; cc < 16; cc += 4) {
    LOADFB(cc+1)
    SPLITX(x00, x01) LOADX(x00,x01, cc+4) MFMAS_A()
    SGB(0x20, 10); SGB(0x8, 12);
    LOADFA(cc+2)
    SPLITX(x10, x11) LOADX(x10,x11, cc+5) MFMAS_B()
    SGB(0x20, 10); SGB(0x8, 12);
    LOADFB(cc+3)
    SPLITX(x20, x21) LOADX(x20,x21, cc+6) MFMAS_A()
    SGB(0x20, 10); SGB(0x8, 12);
    LOADFA(cc+4)
    SPLITX(x30, x31) LOADX(x30,x31, cc+7) MFMAS_B()
    SGB(0x20, 10); SGB(0x8, 12);
  }
  // peeled tail cc = 16 (no x prefetch; exact SGB counts)
  {
    LOADFB(17)
    SPLITX(x00, x01) MFMAS_A()
    SGB(0x20, 8); SGB(0x8, 12);
    LOADFA(18)
    SPLITX(x10, x11) MFMAS_B()
    SGB(0x20, 8); SGB(0x8, 12);
    LOADFB(19)
    SPLITX(x20, x21) MFMAS_A()
    SGB(0x20, 8); SGB(0x8, 12);
    SPLITX(x30, x31) MFMAS_B()
    SGB(0x8, 12);
  }

  // ---------------- softmax (in-register) ----------------
  // lane holds S[row = 4q+j][m = 16g+t]
  float rmax[4], rsum[4];
#pragma unroll
  for (int j = 0; j < 4; ++j)
    rmax[j] = fmaxf(fmaxf(acc[0][j], acc[1][j]), fmaxf(acc[2][j], acc[3][j]));
#pragma unroll
  for (int mk = 1; mk <= 8; mk <<= 1) {
#pragma unroll
    for (int j = 0; j < 4; ++j)
      rmax[j] = fmaxf(rmax[j], __shfl_xor(rmax[j], mk, 64));
  }
#pragma unroll
  for (int g = 0; g < 4; ++g)
#pragma unroll
    for (int j = 0; j < 4; ++j)
      acc[g][j] = exp2f((acc[g][j] - rmax[j]) * 1.44269504f);
#pragma unroll
  for (int j = 0; j < 4; ++j)
    rsum[j] = (acc[0][j] + acc[1][j]) + (acc[2][j] + acc[3][j]);
#pragma unroll
  for (int mk = 1; mk <= 8; mk <<= 1) {
#pragma unroll
    for (int j = 0; j < 4; ++j)
      rsum[j] += __shfl_xor(rsum[j], mk, 64);
  }
#pragma unroll
  for (int j = 0; j < 4; ++j) rsum[j] = 1.0f / rsum[j];

  // W -> private LDS slab, XOR swizzle (proven 0-conflict)
#pragma unroll
  for (int g = 0; g < 4; ++g)
#pragma unroll
    for (int j = 0; j < 4; ++j) {
      float wt = acc[g][j] * rsum[j];
      unsigned short hi, lo;
      splitf(wt, hi, lo);
      int row = 4*q + j;
      int ms  = (16*g + t) ^ ((row & 7) << 3);
      Wh[row][ms] = hi;
      Wl[row][ms] = lo;
    }
  // same-wave cross-lane LDS handoff: wait for all ds_writes to land
  asm volatile("s_waitcnt lgkmcnt(0)" ::: "memory");
  __builtin_amdgcn_sched_barrier(0);

  // hoisted GEMM2 W-fragments: W[row=t][k=32c+8q+j]  (loop-invariant over n)
  short8 aH0, aH1, aL0, aL1;
  {
    const int sw  = (t & 7) << 3;
    const int ms0 = (8*q) ^ sw;
    const int ms1 = (32 + 8*q) ^ sw;
    aH0 = *(const short8*)&Wh[t][ms0];
    aH1 = *(const short8*)&Wh[t][ms1];
    aL0 = *(const short8*)&Wl[t][ms0];
    aL1 = *(const short8*)&Wl[t][ms1];
  }

  // ---------------- GEMM2 (swapped): out = W @ Mv, Mv-hi as A, W as B ----------------
  // mfma(A=MvFrag, B=WFrag) -> lane (t,q) holds out[row0+t][16n+4q+j], j=0..3
  // -> ONE f32x4 NT store per n; paired n gives adjacent 64B segments (128B line).
  short8 vA0, vA1, vB0, vB1;
  {
    const unsigned short* mvp = MvP + l*8;     // n = 0
    vA0 = *(const short8*)(mvp);
    vA1 = *(const short8*)(mvp + 512);
  }
  float* opb = out + (row0 + t) * DDIM + 4*q;

#pragma unroll 2
  for (int n = 0; n < 40; n += 2) {
    {   // prefetch B <- n+1
      const unsigned short* mvp = MvP + (n + 1) * 1024 + l*8;
      vB0 = *(const short8*)(mvp);
      vB1 = *(const short8*)(mvp + 512);
    }
    {   // compute n with A  (4 MFMA: Mv_hi x (Wh+Wl) over both k-halves)
      f32x4 o = (f32x4){0.f,0.f,0.f,0.f};
      o = mfma16(vA0, aH0, o); o = mfma16(vA0, aL0, o);
      o = mfma16(vA1, aH1, o); o = mfma16(vA1, aL1, o);
      __builtin_nontemporal_store(o, (f32x4*)(opb + 16*n));
    }
    if (n + 2 < 40) {   // prefetch A <- n+2
      const unsigned short* mvp = MvP + (n + 2) * 1024 + l*8;
      vA0 = *(const short8*)(mvp);
      vA1 = *(const short8*)(mvp + 512);
    }
    {   // compute n+1 with B
      f32x4 o = (f32x4){0.f,0.f,0.f,0.f};
      o = mfma16(vB0, aH0, o); o = mfma16(vB0, aL0, o);
      o = mfma16(vB1, aH1, o); o = mfma16(vB1, aL1, o);
      __builtin_nontemporal_store(o, (f32x4*)(opb + 16*(n + 1)));
    }
  }
}

extern "C" void kernel_launch(void* const* d_in, const int* in_sizes, int n_in,
                              void* d_out, int out_size, void* d_ws, size_t ws_size,
                              hipStream_t stream) {
  const float* x  = (const float*)d_in[0];
  const float* Mk = (const float*)d_in[1];
  const float* Mv = (const float*)d_in[2];
  float* outp = (float*)d_out;
  unsigned short* ws = (unsigned short*)d_ws;

  ea_pack<<<40, 256, 0, stream>>>(Mk, Mv, ws);
  ea_main<<<4096, 64, 0, stream>>>(x, ws, ws + MVP_OFF, outp);
}

// Round 19
// 83.204 us; speedup vs baseline: 1.0222x; 1.0222x over previous
//
#include <hip/hip_runtime.h>

typedef float  f32x4  __attribute__((ext_vector_type(4)));
typedef short  short8 __attribute__((ext_vector_type(8)));
typedef __bf16 bf16x8 __attribute__((ext_vector_type(8)));

#define DEV static __device__ __forceinline__
// sched_group_barrier masks: VALU=0x2, MFMA=0x8, VMEM_READ=0x20, VMEM_WRITE=0x40
#define SGB(m, n) __builtin_amdgcn_sched_group_barrier((m), (n), 0)

DEV f32x4 mfma16(short8 a, short8 b, f32x4 c) {
  return __builtin_amdgcn_mfma_f32_16x16x32_bf16(
      __builtin_bit_cast(bf16x8, a), __builtin_bit_cast(bf16x8, b), c, 0, 0, 0);
}

// split f32 into bf16 hi (truncated) + bf16 lo (RNE of residual)
DEV void splitf(float f, unsigned short& hi, unsigned short& lo) {
  unsigned u = __builtin_bit_cast(unsigned, f);
  hi = (unsigned short)(u >> 16);
  float hf = __builtin_bit_cast(float, u & 0xFFFF0000u);
  float r = f - hf;
  unsigned v = __builtin_bit_cast(unsigned, r);
  lo = (unsigned short)((v + 0x7FFFu + ((v >> 16) & 1u)) >> 16);
}

// RNE f32 -> bf16
DEV unsigned short rne16(float f) {
  unsigned v = __builtin_bit_cast(unsigned, f);
  return (unsigned short)((v + 0x7FFFu + ((v >> 16) & 1u)) >> 16);
}

#define DDIM 640
#define KCH  20                    // 640 / 32 k-chunks for GEMM1
#define MKP_ELEMS (KCH*2*4*64*8)   // 81920 ushorts = 160KB  (hi+lo planes)
#define MVP_OFF   MKP_ELEMS        // MvP: hi-only, 80KB

// Pack Mk (hi/lo fragment planes) and Mv^T (RNE hi-only) in MFMA fragment order.
// MkP: [c(20)][plane(2)][g(4)][lane(64)][j(8)] holds Mk[m=16g+(l&15)][d=32c+8*(l>>4)+j]
// MvP: [n(40)][c(2)][lane(64)][j(8)]           holds Mv[m=32c+8*(l>>4)+j][d=16n+(l&15)]
__global__ void ea_pack(const float* __restrict__ Mk, const float* __restrict__ Mv,
                        unsigned short* __restrict__ ws) {
  int tid = blockIdx.x * 256 + threadIdx.x;
  unsigned short* MkP = ws;
  unsigned short* MvP = ws + MVP_OFF;
  if (tid < 5120) {
    int c = tid >> 8;
    int g = (tid >> 6) & 3;
    int l = tid & 63;
    int t = l & 15, q = l >> 4;
    const float* src = Mk + (16*g + t) * DDIM + 32*c + 8*q;
    unsigned short* dh = MkP + (((c*2 + 0)*4 + g)*64 + l)*8;
    unsigned short* dl = MkP + (((c*2 + 1)*4 + g)*64 + l)*8;
#pragma unroll
    for (int j = 0; j < 8; ++j) splitf(src[j], dh[j], dl[j]);
  } else if (tid < 10240) {
    int s = tid - 5120;
    int n = s >> 7;
    int c = (s >> 6) & 1;
    int l = s & 63;
    int t = l & 15, q = l >> 4;
    const float* src = Mv + (32*c + 8*q) * DDIM + 16*n + t;
    unsigned short* dh = MvP + ((n*2 + c)*64 + l)*8;
#pragma unroll
    for (int j = 0; j < 8; ++j) dh[j] = rne16(src[j*DDIM]);
  }
}

// ---- GEMM1 helpers (R17 structure, unchanged) ----
#define LOADX(X0, X1, c) { X0 = *(const f32x4*)(xp + 32*(c)); \
                           X1 = *(const f32x4*)(xp + 32*(c) + 4); }

#define LOADFA(c) { const unsigned short* p_ = MkP + (c)*4096 + l*8;         \
  fa0 = *(const short8*)(p_);        fa1 = *(const short8*)(p_ + 512);       \
  fa2 = *(const short8*)(p_ + 1024); fa3 = *(const short8*)(p_ + 1536);      \
  fa4 = *(const short8*)(p_ + 2048); fa5 = *(const short8*)(p_ + 2560);      \
  fa6 = *(const short8*)(p_ + 3072); fa7 = *(const short8*)(p_ + 3584); }

#define LOADFB(c) { const unsigned short* p_ = MkP + (c)*4096 + l*8;         \
  fb0 = *(const short8*)(p_);        fb1 = *(const short8*)(p_ + 512);       \
  fb2 = *(const short8*)(p_ + 1024); fb3 = *(const short8*)(p_ + 1536);      \
  fb4 = *(const short8*)(p_ + 2048); fb5 = *(const short8*)(p_ + 2560);      \
  fb6 = *(const short8*)(p_ + 3072); fb7 = *(const short8*)(p_ + 3584); }

#define SPLITX(X0, X1)                                                       \
  splitf(X0[0], ah.u[0], al.u[0]); splitf(X0[1], ah.u[1], al.u[1]);          \
  splitf(X0[2], ah.u[2], al.u[2]); splitf(X0[3], ah.u[3], al.u[3]);          \
  splitf(X1[0], ah.u[4], al.u[4]); splitf(X1[1], ah.u[5], al.u[5]);          \
  splitf(X1[2], ah.u[6], al.u[6]); splitf(X1[3], ah.u[7], al.u[7]);

#define MFMAS_A()                                                            \
  acc[0] = mfma16(ah.s, fa0, acc[0]); acc[1] = mfma16(ah.s, fa1, acc[1]);    \
  acc[2] = mfma16(ah.s, fa2, acc[2]); acc[3] = mfma16(ah.s, fa3, acc[3]);    \
  acc[0] = mfma16(al.s, fa0, acc[0]); acc[1] = mfma16(al.s, fa1, acc[1]);    \
  acc[2] = mfma16(al.s, fa2, acc[2]); acc[3] = mfma16(al.s, fa3, acc[3]);    \
  acc[0] = mfma16(ah.s, fa4, acc[0]); acc[1] = mfma16(ah.s, fa5, acc[1]);    \
  acc[2] = mfma16(ah.s, fa6, acc[2]); acc[3] = mfma16(ah.s, fa7, acc[3]);

#define MFMAS_B()                                                            \
  acc[0] = mfma16(ah.s, fb0, acc[0]); acc[1] = mfma16(ah.s, fb1, acc[1]);    \
  acc[2] = mfma16(ah.s, fb2, acc[2]); acc[3] = mfma16(ah.s, fb3, acc[3]);    \
  acc[0] = mfma16(al.s, fb0, acc[0]); acc[1] = mfma16(al.s, fb1, acc[1]);    \
  acc[2] = mfma16(al.s, fb2, acc[2]); acc[3] = mfma16(al.s, fb3, acc[3]);    \
  acc[0] = mfma16(ah.s, fb4, acc[0]); acc[1] = mfma16(ah.s, fb5, acc[1]);    \
  acc[2] = mfma16(ah.s, fb6, acc[2]); acc[3] = mfma16(ah.s, fb7, acc[3]);

// FOUR waves per block (256 threads), each wave owns 16 rows end-to-end with
// NO barriers (private LDS slab per wave). Grid 1024 -> 4 blocks/CU = 16
// waves/CU, same TLP as R17 — but the 4 waves of a block run in natural
// lockstep through the SAME MkP chunk sequence, so the CU's active fragment
// set is 4 blocks x 8KB = 32KB = L1 (vs 16 x 8KB = 128KB with 1-wave blocks):
// ~3 of 4 LOADFs become L1 hits.
__global__
__attribute__((amdgpu_flat_work_group_size(256, 256), amdgpu_waves_per_eu(4, 4)))
void ea_main(const float* __restrict__ x,
             const unsigned short* __restrict__ MkP,
             const unsigned short* __restrict__ MvP,
             float* __restrict__ out) {
  __shared__ __align__(16) unsigned short Wh[4][16][64];
  __shared__ __align__(16) unsigned short Wl[4][16][64];
  const int tid = threadIdx.x;
  const int w = tid >> 6;             // wave 0..3
  const int l = tid & 63;
  const int t = l & 15;
  const int q = l >> 4;
  const long row0 = (long)blockIdx.x * 64 + 16*w;

  // ---------------- GEMM1: scores ----------------
  const float* xp = x + (row0 + t) * DDIM + 8*q;
  f32x4 acc[4];
#pragma unroll
  for (int g = 0; g < 4; ++g) acc[g] = (f32x4){0.f, 0.f, 0.f, 0.f};

  f32x4 x00,x01,x10,x11,x20,x21,x30,x31;
  short8 fa0,fa1,fa2,fa3,fa4,fa5,fa6,fa7;        // frag set A (even chunks)
  short8 fb0,fb1,fb2,fb3,fb4,fb5,fb6,fb7;        // frag set B (odd chunks)
  union { short8 s; unsigned short u[8]; } ah, al;

  LOADX(x00,x01, 0) LOADX(x10,x11, 1) LOADX(x20,x21, 2) LOADX(x30,x31, 3)
  LOADFA(0)

  // main iters cc = 0,4,8,12 (all have cc+4 <= 16 < 20: x prefetch active)
#pragma unroll
  for (int cc = 0; cc < 16; cc += 4) {
    LOADFB(cc+1)
    SPLITX(x00, x01) LOADX(x00,x01, cc+4) MFMAS_A()
    SGB(0x20, 10); SGB(0x8, 12);
    LOADFA(cc+2)
    SPLITX(x10, x11) LOADX(x10,x11, cc+5) MFMAS_B()
    SGB(0x20, 10); SGB(0x8, 12);
    LOADFB(cc+3)
    SPLITX(x20, x21) LOADX(x20,x21, cc+6) MFMAS_A()
    SGB(0x20, 10); SGB(0x8, 12);
    LOADFA(cc+4)
    SPLITX(x30, x31) LOADX(x30,x31, cc+7) MFMAS_B()
    SGB(0x20, 10); SGB(0x8, 12);
  }
  // peeled tail cc = 16 (no x prefetch; exact SGB counts)
  {
    LOADFB(17)
    SPLITX(x00, x01) MFMAS_A()
    SGB(0x20, 8); SGB(0x8, 12);
    LOADFA(18)
    SPLITX(x10, x11) MFMAS_B()
    SGB(0x20, 8); SGB(0x8, 12);
    LOADFB(19)
    SPLITX(x20, x21) MFMAS_A()
    SGB(0x20, 8); SGB(0x8, 12);
    SPLITX(x30, x31) MFMAS_B()
    SGB(0x8, 12);
  }

  // ---------------- softmax (in-register) ----------------
  // lane holds S[row = 4q+j][m = 16g+t]
  float rmax[4], rsum[4];
#pragma unroll
  for (int j = 0; j < 4; ++j)
    rmax[j] = fmaxf(fmaxf(acc[0][j], acc[1][j]), fmaxf(acc[2][j], acc[3][j]));
#pragma unroll
  for (int mk = 1; mk <= 8; mk <<= 1) {
#pragma unroll
    for (int j = 0; j < 4; ++j)
      rmax[j] = fmaxf(rmax[j], __shfl_xor(rmax[j], mk, 64));
  }
#pragma unroll
  for (int g = 0; g < 4; ++g)
#pragma unroll
    for (int j = 0; j < 4; ++j)
      acc[g][j] = exp2f((acc[g][j] - rmax[j]) * 1.44269504f);
#pragma unroll
  for (int j = 0; j < 4; ++j)
    rsum[j] = (acc[0][j] + acc[1][j]) + (acc[2][j] + acc[3][j]);
#pragma unroll
  for (int mk = 1; mk <= 8; mk <<= 1) {
#pragma unroll
    for (int j = 0; j < 4; ++j)
      rsum[j] += __shfl_xor(rsum[j], mk, 64);
  }
#pragma unroll
  for (int j = 0; j < 4; ++j) rsum[j] = 1.0f / rsum[j];

  // W -> this wave's private LDS slab, XOR swizzle (proven 0-conflict)
#pragma unroll
  for (int g = 0; g < 4; ++g)
#pragma unroll
    for (int j = 0; j < 4; ++j) {
      float wt = acc[g][j] * rsum[j];
      unsigned short hi, lo;
      splitf(wt, hi, lo);
      int row = 4*q + j;
      int ms  = (16*g + t) ^ ((row & 7) << 3);
      Wh[w][row][ms] = hi;
      Wl[w][row][ms] = lo;
    }
  // same-wave cross-lane LDS handoff: wait for all ds_writes to land
  asm volatile("s_waitcnt lgkmcnt(0)" ::: "memory");
  __builtin_amdgcn_sched_barrier(0);

  // hoisted GEMM2 W-fragments: W[row=t][k=32c+8q+j]  (loop-invariant over n)
  short8 aH0, aH1, aL0, aL1;
  {
    const int sw  = (t & 7) << 3;
    const int ms0 = (8*q) ^ sw;
    const int ms1 = (32 + 8*q) ^ sw;
    aH0 = *(const short8*)&Wh[w][t][ms0];
    aH1 = *(const short8*)&Wh[w][t][ms1];
    aL0 = *(const short8*)&Wl[w][t][ms0];
    aL1 = *(const short8*)&Wl[w][t][ms1];
  }

  // ---------------- GEMM2: out = W @ Mv (Mv hi-only), named A/B buffers ----------------
  short8 vA0, vA1, vB0, vB1;
  {
    const unsigned short* mvp = MvP + l*8;     // n = 0
    vA0 = *(const short8*)(mvp);
    vA1 = *(const short8*)(mvp + 512);
  }
  float* opb = out + (row0 + 4*q) * DDIM + t;

#pragma unroll 2
  for (int n = 0; n < 40; n += 2) {
    {   // prefetch B <- n+1
      const unsigned short* mvp = MvP + (n + 1) * 1024 + l*8;
      vB0 = *(const short8*)(mvp);
      vB1 = *(const short8*)(mvp + 512);
    }
    {   // compute n with A  (4 MFMA: (Wh+Wl) x Mv_hi over both k-halves)
      f32x4 o = (f32x4){0.f,0.f,0.f,0.f};
      o = mfma16(aH0, vA0, o); o = mfma16(aL0, vA0, o);
      o = mfma16(aH1, vA1, o); o = mfma16(aL1, vA1, o);
      float* op = opb + 16*n;
#pragma unroll
      for (int j = 0; j < 4; ++j) __builtin_nontemporal_store(o[j], op + j*DDIM);
    }
    if (n + 2 < 40) {   // prefetch A <- n+2
      const unsigned short* mvp = MvP + (n + 2) * 1024 + l*8;
      vA0 = *(const short8*)(mvp);
      vA1 = *(const short8*)(mvp + 512);
    }
    {   // compute n+1 with B
      f32x4 o = (f32x4){0.f,0.f,0.f,0.f};
      o = mfma16(aH0, vB0, o); o = mfma16(aL0, vB0, o);
      o = mfma16(aH1, vB1, o); o = mfma16(aL1, vB1, o);
      float* op = opb + 16*(n + 1);
#pragma unroll
      for (int j = 0; j < 4; ++j) __builtin_nontemporal_store(o[j], op + j*DDIM);
    }
  }
}

extern "C" void kernel_launch(void* const* d_in, const int* in_sizes, int n_in,
                              void* d_out, int out_size, void* d_ws, size_t ws_size,
                              hipStream_t stream) {
  const float* x  = (const float*)d_in[0];
  const float* Mk = (const float*)d_in[1];
  const float* Mv = (const float*)d_in[2];
  float* outp = (float*)d_out;
  unsigned short* ws = (unsigned short*)d_ws;

  ea_pack<<<40, 256, 0, stream>>>(Mk, Mv, ws);
  ea_main<<<1024, 256, 0, stream>>>(x, ws, ws + MVP_OFF, outp);
}

// Round 20
// 82.362 us; speedup vs baseline: 1.0326x; 1.0102x over previous
//
#include <hip/hip_runtime.h>

typedef float  f32x4  __attribute__((ext_vector_type(4)));
typedef short  short8 __attribute__((ext_vector_type(8)));
typedef __bf16 bf16x8 __attribute__((ext_vector_type(8)));

#define DEV static __device__ __forceinline__
// sched_group_barrier masks: VALU=0x2, MFMA=0x8, VMEM_READ=0x20, VMEM_WRITE=0x40
#define SGB(m, n) __builtin_amdgcn_sched_group_barrier((m), (n), 0)

DEV f32x4 mfma16(short8 a, short8 b, f32x4 c) {
  return __builtin_amdgcn_mfma_f32_16x16x32_bf16(
      __builtin_bit_cast(bf16x8, a), __builtin_bit_cast(bf16x8, b), c, 0, 0, 0);
}

// split f32 into bf16 hi (truncated) + bf16 lo (RNE of residual)
DEV void splitf(float f, unsigned short& hi, unsigned short& lo) {
  unsigned u = __builtin_bit_cast(unsigned, f);
  hi = (unsigned short)(u >> 16);
  float hf = __builtin_bit_cast(float, u & 0xFFFF0000u);
  float r = f - hf;
  unsigned v = __builtin_bit_cast(unsigned, r);
  lo = (unsigned short)((v + 0x7FFFu + ((v >> 16) & 1u)) >> 16);
}

// RNE f32 -> bf16
DEV unsigned short rne16(float f) {
  unsigned v = __builtin_bit_cast(unsigned, f);
  return (unsigned short)((v + 0x7FFFu + ((v >> 16) & 1u)) >> 16);
}

#define DDIM 640
#define KCH  20                    // 640 / 32 k-chunks for GEMM1
#define MKP_ELEMS (KCH*2*4*64*8)   // 81920 ushorts = 160KB  (hi+lo planes)
#define MVP_OFF   MKP_ELEMS        // MvP: hi-only, 80KB

// Pack Mk (hi/lo fragment planes) and Mv^T (RNE hi-only) in MFMA fragment order.
// MkP: [c(20)][plane(2)][g(4)][lane(64)][j(8)] holds Mk[m=16g+(l&15)][d=32c+8*(l>>4)+j]
// MvP: [n(40)][c(2)][lane(64)][j(8)]           holds Mv[m=32c+8*(l>>4)+j][d=16n+(l&15)]
__global__ void ea_pack(const float* __restrict__ Mk, const float* __restrict__ Mv,
                        unsigned short* __restrict__ ws) {
  int tid = blockIdx.x * 256 + threadIdx.x;
  unsigned short* MkP = ws;
  unsigned short* MvP = ws + MVP_OFF;
  if (tid < 5120) {
    int c = tid >> 8;
    int g = (tid >> 6) & 3;
    int l = tid & 63;
    int t = l & 15, q = l >> 4;
    const float* src = Mk + (16*g + t) * DDIM + 32*c + 8*q;
    unsigned short* dh = MkP + (((c*2 + 0)*4 + g)*64 + l)*8;
    unsigned short* dl = MkP + (((c*2 + 1)*4 + g)*64 + l)*8;
#pragma unroll
    for (int j = 0; j < 8; ++j) splitf(src[j], dh[j], dl[j]);
  } else if (tid < 10240) {
    int s = tid - 5120;
    int n = s >> 7;
    int c = (s >> 6) & 1;
    int l = s & 63;
    int t = l & 15, q = l >> 4;
    const float* src = Mv + (32*c + 8*q) * DDIM + 16*n + t;
    unsigned short* dh = MvP + ((n*2 + c)*64 + l)*8;
#pragma unroll
    for (int j = 0; j < 8; ++j) dh[j] = rne16(src[j*DDIM]);
  }
}

// ---- GEMM1 helpers (R17 structure, unchanged) ----
#define LOADX(X0, X1, c) { X0 = *(const f32x4*)(xp + 32*(c)); \
                           X1 = *(const f32x4*)(xp + 32*(c) + 4); }

#define LOADFA(c) { const unsigned short* p_ = MkP + (c)*4096 + l*8;         \
  fa0 = *(const short8*)(p_);        fa1 = *(const short8*)(p_ + 512);       \
  fa2 = *(const short8*)(p_ + 1024); fa3 = *(const short8*)(p_ + 1536);      \
  fa4 = *(const short8*)(p_ + 2048); fa5 = *(const short8*)(p_ + 2560);      \
  fa6 = *(const short8*)(p_ + 3072); fa7 = *(const short8*)(p_ + 3584); }

#define LOADFB(c) { const unsigned short* p_ = MkP + (c)*4096 + l*8;         \
  fb0 = *(const short8*)(p_);        fb1 = *(const short8*)(p_ + 512);       \
  fb2 = *(const short8*)(p_ + 1024); fb3 = *(const short8*)(p_ + 1536);      \
  fb4 = *(const short8*)(p_ + 2048); fb5 = *(const short8*)(p_ + 2560);      \
  fb6 = *(const short8*)(p_ + 3072); fb7 = *(const short8*)(p_ + 3584); }

#define SPLITX(X0, X1)                                                       \
  splitf(X0[0], ah.u[0], al.u[0]); splitf(X0[1], ah.u[1], al.u[1]);          \
  splitf(X0[2], ah.u[2], al.u[2]); splitf(X0[3], ah.u[3], al.u[3]);          \
  splitf(X1[0], ah.u[4], al.u[4]); splitf(X1[1], ah.u[5], al.u[5]);          \
  splitf(X1[2], ah.u[6], al.u[6]); splitf(X1[3], ah.u[7], al.u[7]);

#define MFMAS_A()                                                            \
  acc[0] = mfma16(ah.s, fa0, acc[0]); acc[1] = mfma16(ah.s, fa1, acc[1]);    \
  acc[2] = mfma16(ah.s, fa2, acc[2]); acc[3] = mfma16(ah.s, fa3, acc[3]);    \
  acc[0] = mfma16(al.s, fa0, acc[0]); acc[1] = mfma16(al.s, fa1, acc[1]);    \
  acc[2] = mfma16(al.s, fa2, acc[2]); acc[3] = mfma16(al.s, fa3, acc[3]);    \
  acc[0] = mfma16(ah.s, fa4, acc[0]); acc[1] = mfma16(ah.s, fa5, acc[1]);    \
  acc[2] = mfma16(ah.s, fa6, acc[2]); acc[3] = mfma16(ah.s, fa7, acc[3]);

#define MFMAS_B()                                                            \
  acc[0] = mfma16(ah.s, fb0, acc[0]); acc[1] = mfma16(ah.s, fb1, acc[1]);    \
  acc[2] = mfma16(ah.s, fb2, acc[2]); acc[3] = mfma16(ah.s, fb3, acc[3]);    \
  acc[0] = mfma16(al.s, fb0, acc[0]); acc[1] = mfma16(al.s, fb1, acc[1]);    \
  acc[2] = mfma16(al.s, fb2, acc[2]); acc[3] = mfma16(al.s, fb3, acc[3]);    \
  acc[0] = mfma16(ah.s, fb4, acc[0]); acc[1] = mfma16(ah.s, fb5, acc[1]);    \
  acc[2] = mfma16(ah.s, fb6, acc[2]); acc[3] = mfma16(ah.s, fb7, acc[3]);

// One wave per block (64 threads), 16 rows/wave, grid 4096 -> 16 blocks/CU.
// Independent waves, no barriers. GEMM1 frag ping-pong with SGB-pinned issue
// order; softmax in-register; W via XOR-swizzled LDS; GEMM2 Mv hi-only A/B;
// NT stores issued as back-to-back 64B partners of each 128B line.
__global__
__attribute__((amdgpu_flat_work_group_size(64, 64), amdgpu_waves_per_eu(4, 4)))
void ea_main(const float* __restrict__ x,
             const unsigned short* __restrict__ MkP,
             const unsigned short* __restrict__ MvP,
             float* __restrict__ out) {
  __shared__ __align__(16) unsigned short Wh[16][64];
  __shared__ __align__(16) unsigned short Wl[16][64];
  const int l = threadIdx.x;          // 0..63
  const int t = l & 15;
  const int q = l >> 4;
  const long row0 = (long)blockIdx.x * 16;

  // ---------------- GEMM1: scores ----------------
  const float* xp = x + (row0 + t) * DDIM + 8*q;
  f32x4 acc[4];
#pragma unroll
  for (int g = 0; g < 4; ++g) acc[g] = (f32x4){0.f, 0.f, 0.f, 0.f};

  f32x4 x00,x01,x10,x11,x20,x21,x30,x31;
  short8 fa0,fa1,fa2,fa3,fa4,fa5,fa6,fa7;        // frag set A (even chunks)
  short8 fb0,fb1,fb2,fb3,fb4,fb5,fb6,fb7;        // frag set B (odd chunks)
  union { short8 s; unsigned short u[8]; } ah, al;

  LOADX(x00,x01, 0) LOADX(x10,x11, 1) LOADX(x20,x21, 2) LOADX(x30,x31, 3)
  LOADFA(0)

  // main iters cc = 0,4,8,12 (all have cc+4 <= 16 < 20: x prefetch active)
#pragma unroll
  for (int cc = 0; cc < 16; cc += 4) {
    LOADFB(cc+1)
    SPLITX(x00, x01) LOADX(x00,x01, cc+4) MFMAS_A()
    SGB(0x20, 10); SGB(0x8, 12);
    LOADFA(cc+2)
    SPLITX(x10, x11) LOADX(x10,x11, cc+5) MFMAS_B()
    SGB(0x20, 10); SGB(0x8, 12);
    LOADFB(cc+3)
    SPLITX(x20, x21) LOADX(x20,x21, cc+6) MFMAS_A()
    SGB(0x20, 10); SGB(0x8, 12);
    LOADFA(cc+4)
    SPLITX(x30, x31) LOADX(x30,x31, cc+7) MFMAS_B()
    SGB(0x20, 10); SGB(0x8, 12);
  }
  // peeled tail cc = 16 (no x prefetch; exact SGB counts)
  {
    LOADFB(17)
    SPLITX(x00, x01) MFMAS_A()
    SGB(0x20, 8); SGB(0x8, 12);
    LOADFA(18)
    SPLITX(x10, x11) MFMAS_B()
    SGB(0x20, 8); SGB(0x8, 12);
    LOADFB(19)
    SPLITX(x20, x21) MFMAS_A()
    SGB(0x20, 8); SGB(0x8, 12);
    SPLITX(x30, x31) MFMAS_B()
    SGB(0x8, 12);
  }

  // ---------------- softmax (in-register) ----------------
  // lane holds S[row = 4q+j][m = 16g+t]
  float rmax[4], rsum[4];
#pragma unroll
  for (int j = 0; j < 4; ++j)
    rmax[j] = fmaxf(fmaxf(acc[0][j], acc[1][j]), fmaxf(acc[2][j], acc[3][j]));
#pragma unroll
  for (int mk = 1; mk <= 8; mk <<= 1) {
#pragma unroll
    for (int j = 0; j < 4; ++j)
      rmax[j] = fmaxf(rmax[j], __shfl_xor(rmax[j], mk, 64));
  }
#pragma unroll
  for (int g = 0; g < 4; ++g)
#pragma unroll
    for (int j = 0; j < 4; ++j)
      acc[g][j] = exp2f((acc[g][j] - rmax[j]) * 1.44269504f);
#pragma unroll
  for (int j = 0; j < 4; ++j)
    rsum[j] = (acc[0][j] + acc[1][j]) + (acc[2][j] + acc[3][j]);
#pragma unroll
  for (int mk = 1; mk <= 8; mk <<= 1) {
#pragma unroll
    for (int j = 0; j < 4; ++j)
      rsum[j] += __shfl_xor(rsum[j], mk, 64);
  }
#pragma unroll
  for (int j = 0; j < 4; ++j) rsum[j] = 1.0f / rsum[j];

  // W -> private LDS slab, XOR swizzle (proven 0-conflict)
#pragma unroll
  for (int g = 0; g < 4; ++g)
#pragma unroll
    for (int j = 0; j < 4; ++j) {
      float wt = acc[g][j] * rsum[j];
      unsigned short hi, lo;
      splitf(wt, hi, lo);
      int row = 4*q + j;
      int ms  = (16*g + t) ^ ((row & 7) << 3);
      Wh[row][ms] = hi;
      Wl[row][ms] = lo;
    }
  // same-wave cross-lane LDS handoff: wait for all ds_writes to land
  asm volatile("s_waitcnt lgkmcnt(0)" ::: "memory");
  __builtin_amdgcn_sched_barrier(0);

  // hoisted GEMM2 W-fragments: W[row=t][k=32c+8q+j]  (loop-invariant over n)
  short8 aH0, aH1, aL0, aL1;
  {
    const int sw  = (t & 7) << 3;
    const int ms0 = (8*q) ^ sw;
    const int ms1 = (32 + 8*q) ^ sw;
    aH0 = *(const short8*)&Wh[t][ms0];
    aH1 = *(const short8*)&Wh[t][ms1];
    aL0 = *(const short8*)&Wl[t][ms0];
    aL1 = *(const short8*)&Wl[t][ms1];
  }

  // ---------------- GEMM2: out = W @ Mv (Mv hi-only) ----------------
  // Compute the n-pair FIRST, then store interleaved: for each j, the oA
  // store (cols 16n, 64B) is immediately followed by the oB store (cols
  // 16n+16 — the other half of the SAME 128B line; n even + 2560B row
  // stride => line-aligned). Back-to-back issue lets the NT write path
  // combine the halves instead of flushing 64B granules (the 225 vs
  // 168MB WRITE_SIZE amplification).
  short8 vA0, vA1, vB0, vB1;
  {
    const unsigned short* mvp = MvP + l*8;     // n = 0
    vA0 = *(const short8*)(mvp);
    vA1 = *(const short8*)(mvp + 512);
  }
  float* opb = out + (row0 + 4*q) * DDIM + t;

#pragma unroll 2
  for (int n = 0; n < 40; n += 2) {
    {   // prefetch B <- n+1
      const unsigned short* mvp = MvP + (n + 1) * 1024 + l*8;
      vB0 = *(const short8*)(mvp);
      vB1 = *(const short8*)(mvp + 512);
    }
    f32x4 oA;
    {   // compute n with A  (4 MFMA: (Wh+Wl) x Mv_hi over both k-halves)
      f32x4 o = (f32x4){0.f,0.f,0.f,0.f};
      o = mfma16(aH0, vA0, o); o = mfma16(aL0, vA0, o);
      o = mfma16(aH1, vA1, o); o = mfma16(aL1, vA1, o);
      oA = o;
    }
    if (n + 2 < 40) {   // prefetch A <- n+2
      const unsigned short* mvp = MvP + (n + 2) * 1024 + l*8;
      vA0 = *(const short8*)(mvp);
      vA1 = *(const short8*)(mvp + 512);
    }
    f32x4 oB;
    {   // compute n+1 with B
      f32x4 o = (f32x4){0.f,0.f,0.f,0.f};
      o = mfma16(aH0, vB0, o); o = mfma16(aL0, vB0, o);
      o = mfma16(aH1, vB1, o); o = mfma16(aL1, vB1, o);
      oB = o;
    }
    {   // interleaved NT stores: 128B-line partners issued back-to-back
      float* opA = opb + 16*n;
      float* opB = opA + 16;
#pragma unroll
      for (int j = 0; j < 4; ++j) {
        __builtin_nontemporal_store(oA[j], opA + j*DDIM);
        __builtin_nontemporal_store(oB[j], opB + j*DDIM);
      }
      SGB(0x40, 8);   // cluster the 8 stores contiguously in issue order
    }
  }
}

extern "C" void kernel_launch(void* const* d_in, const int* in_sizes, int n_in,
                              void* d_out, int out_size, void* d_ws, size_t ws_size,
                              hipStream_t stream) {
  const float* x  = (const float*)d_in[0];
  const float* Mk = (const float*)d_in[1];
  const float* Mv = (const float*)d_in[2];
  float* outp = (float*)d_out;
  unsigned short* ws = (unsigned short*)d_ws;

  ea_pack<<<40, 256, 0, stream>>>(Mk, Mv, ws);
  ea_main<<<4096, 64, 0, stream>>>(x, ws, ws + MVP_OFF, outp);
}